// Round 1
// baseline (1725.791 us; speedup 1.0000x reference)
//
#include <hip/hip_runtime.h>

// VQ codebook quantization, MI355X fp32 vector path.
// B=8192, d_latent=512, ncb=2, K=8192, d_sub=256.
// Outputs (flat fp32): quantized[8192*512], indices[16384], commitment, codebook, perplexity.

#define KCODES 8192
#define DSUB   256
#define NCB    2
#define BROWS  8192
#define NROWS  (BROWS * NCB)     // 16384 rows of 256 (both z-split and emb rows)

#define QUANT_N  (BROWS * 512)   // 4194304
#define IDX_OFF  QUANT_N
#define LOSS_OFF (QUANT_N + NROWS)

// ws layout (bytes)
#define WS_ESQ    0          // 16384 f32
#define WS_ZSQ    65536      // 16384 f32
#define WS_IDX    131072     // 16384 i32
#define WS_COUNTS 196608     // 16384 i32  (zeroed)
#define WS_LOSS   262144     // 1 f32      (zeroed)

// ---------------------------------------------------------------- sq kernel
// rows [0, NROWS)        -> e_sq over embedding rows (n*K + k)
// rows [NROWS, 2*NROWS)  -> z_sq over z rows (rz = b*2 + n; z flat = rz*256)
__global__ void sq_kernel(const float* __restrict__ z, const float* __restrict__ e,
                          float* __restrict__ e_sq, float* __restrict__ z_sq) {
  int row  = blockIdx.x * 4 + (threadIdx.x >> 6);
  int lane = threadIdx.x & 63;
  const float* src;
  float* dst;
  int r;
  if (row < NROWS) { r = row;         src = e + (size_t)r * DSUB; dst = e_sq; }
  else             { r = row - NROWS; src = z + (size_t)r * DSUB; dst = z_sq; }
  float4 v = ((const float4*)src)[lane];
  float s = v.x * v.x + v.y * v.y + v.z * v.z + v.w * v.w;
  #pragma unroll
  for (int off = 32; off; off >>= 1) s += __shfl_down(s, off, 64);
  if (lane == 0) dst[r] = s;
}

// ------------------------------------------------------------ argmin kernel
// One block per (codebook n, 64-row b-tile): 256 blocks, 256 threads.
// LDS: full-d z tile (64x256) + k-chunk e tile (64x256), padded stride 260.
#define BT  64
#define KT  64
#define LDZ 260

__global__ __launch_bounds__(256, 1)
void argmin_kernel(const float* __restrict__ z, const float* __restrict__ emb,
                   const float* __restrict__ e_sq, const float* __restrict__ z_sq,
                   int* __restrict__ out_idx, int* __restrict__ counts) {
  __shared__ float zs[BT * LDZ];
  __shared__ float es[KT * LDZ];

  const int n   = blockIdx.x & 1;
  const int bt  = blockIdx.x >> 1;
  const int b0  = bt * BT;
  const int tid = threadIdx.x;
  const int tx  = tid & 15;   // col group
  const int ty  = tid >> 4;   // row group

  // stage z tile: 64 rows x 256 d (row rz = (b0+r)*2 + n in flat [16384,256] view)
  #pragma unroll
  for (int i = 0; i < 16; ++i) {
    int flat = i * 256 + tid;          // 0..4095 = 64 rows x 64 float4
    int r    = flat >> 6;
    int d4   = flat & 63;
    float4 v = ((const float4*)(z + ((size_t)((b0 + r) * 2 + n)) * DSUB))[d4];
    *(float4*)&zs[r * LDZ + d4 * 4] = v;
  }

  float zq[4];
  float best[4];
  int   bidx[4];
  #pragma unroll
  for (int i = 0; i < 4; ++i) {
    best[i] = 3.4e38f;
    bidx[i] = 0;
    zq[i]   = z_sq[(size_t)(b0 + ty * 4 + i) * 2 + n];
  }

  const float* ebase = emb + (size_t)n * KCODES * DSUB;
  const float* esq   = e_sq + n * KCODES;

  for (int k0 = 0; k0 < KCODES; k0 += KT) {
    __syncthreads();  // protect es against previous-iteration readers
    #pragma unroll
    for (int i = 0; i < 16; ++i) {
      int flat = i * 256 + tid;
      int r    = flat >> 6;
      int d4   = flat & 63;
      float4 v = ((const float4*)(ebase + ((size_t)(k0 + r)) * DSUB))[d4];
      *(float4*)&es[r * LDZ + d4 * 4] = v;
    }
    __syncthreads();

    float acc[4][4];
    #pragma unroll
    for (int i = 0; i < 4; ++i)
      #pragma unroll
      for (int j = 0; j < 4; ++j) acc[i][j] = 0.0f;

    for (int d0 = 0; d0 < DSUB; d0 += 4) {
      float4 za[4], eb[4];
      #pragma unroll
      for (int i = 0; i < 4; ++i) za[i] = *(const float4*)&zs[(ty * 4 + i) * LDZ + d0];
      #pragma unroll
      for (int j = 0; j < 4; ++j) eb[j] = *(const float4*)&es[(tx * 4 + j) * LDZ + d0];
      #pragma unroll
      for (int i = 0; i < 4; ++i)
        #pragma unroll
        for (int j = 0; j < 4; ++j) {
          acc[i][j] += za[i].x * eb[j].x;
          acc[i][j] += za[i].y * eb[j].y;
          acc[i][j] += za[i].z * eb[j].z;
          acc[i][j] += za[i].w * eb[j].w;
        }
    }

    // fp32 combine exactly as reference: (z_sq - 2*c) + e_sq; ties keep lowest k
    #pragma unroll
    for (int i = 0; i < 4; ++i)
      #pragma unroll
      for (int j = 0; j < 4; ++j) {
        int   k    = k0 + tx * 4 + j;
        float t    = zq[i] - 2.0f * acc[i][j];
        float dist = t + esq[k];
        if (dist < best[i]) { best[i] = dist; bidx[i] = k; }
      }
  }

  // reduce over the 16 tx-lanes sharing each row (lanes grouped by ty)
  #pragma unroll
  for (int i = 0; i < 4; ++i) {
    float v  = best[i];
    int   id = bidx[i];
    #pragma unroll
    for (int off = 8; off; off >>= 1) {
      float v2 = __shfl_down(v, off, 16);
      int   i2 = __shfl_down(id, off, 16);
      if (v2 < v || (v2 == v && i2 < id)) { v = v2; id = i2; }
    }
    if (tx == 0) {
      int row = b0 + ty * 4 + i;
      out_idx[row * 2 + n] = id;
      atomicAdd(&counts[n * KCODES + id], 1);
    }
  }
}

// ------------------------------------------------------- gather/loss kernel
// One wave per row rz = b*2+n: write quantized, index (as float), loss partial.
__global__ void gather_kernel(const float* __restrict__ z, const float* __restrict__ emb,
                              const int* __restrict__ idx, float* __restrict__ out,
                              float* __restrict__ loss) {
  int row  = blockIdx.x * 4 + (threadIdx.x >> 6);
  int lane = threadIdx.x & 63;
  int n = row & 1;
  int k = idx[row];
  float4 ev = ((const float4*)(emb + ((size_t)n * KCODES + k) * DSUB))[lane];
  float4 zv = ((const float4*)(z + (size_t)row * DSUB))[lane];
  ((float4*)out)[(size_t)row * 64 + lane] = ev;   // quantized == z_q numerically
  float dx = zv.x - ev.x, dy = zv.y - ev.y, dz = zv.z - ev.z, dw = zv.w - ev.w;
  float s = dx * dx + dy * dy + dz * dz + dw * dw;
  #pragma unroll
  for (int off = 32; off; off >>= 1) s += __shfl_down(s, off, 64);
  if (lane == 0) {
    atomicAdd(loss, s);
    out[IDX_OFF + row] = (float)k;
  }
}

// ------------------------------------------------------------ final kernel
__global__ void final_kernel(const int* __restrict__ counts, const float* __restrict__ loss,
                             float* __restrict__ out) {
  __shared__ float red[256];
  float h = 0.0f;
  for (int k = threadIdx.x; k < KCODES; k += 256) {
    float p = (float)(counts[k] + counts[KCODES + k]) * (1.0f / 16384.0f);
    h -= p * logf(p + 1e-10f);
  }
  red[threadIdx.x] = h;
  __syncthreads();
  for (int s = 128; s; s >>= 1) {
    if (threadIdx.x < s) red[threadIdx.x] += red[threadIdx.x + s];
    __syncthreads();
  }
  if (threadIdx.x == 0) {
    out[LOSS_OFF + 0] = 0.25f * loss[0] * (1.0f / (float)QUANT_N);
    out[LOSS_OFF + 1] = 0.0f;   // codebook_loss (EMA/eval)
    out[LOSS_OFF + 2] = expf(red[0]);
  }
}

extern "C" void kernel_launch(void* const* d_in, const int* in_sizes, int n_in,
                              void* d_out, int out_size, void* d_ws, size_t ws_size,
                              hipStream_t stream) {
  const float* z   = (const float*)d_in[0];
  const float* emb = (const float*)d_in[1];
  float* out = (float*)d_out;
  char*  ws  = (char*)d_ws;

  float* e_sq   = (float*)(ws + WS_ESQ);
  float* z_sq   = (float*)(ws + WS_ZSQ);
  int*   idx    = (int*)(ws + WS_IDX);
  int*   counts = (int*)(ws + WS_COUNTS);
  float* loss   = (float*)(ws + WS_LOSS);

  hipMemsetAsync(ws + WS_COUNTS, 0, 65536 + 16, stream);
  sq_kernel<<<8192, 256, 0, stream>>>(z, emb, e_sq, z_sq);
  argmin_kernel<<<256, 256, 0, stream>>>(z, emb, e_sq, z_sq, idx, counts);
  gather_kernel<<<4096, 256, 0, stream>>>(z, emb, idx, out, loss);
  final_kernel<<<1, 256, 0, stream>>>(counts, loss, out);
}

// Round 2
// 622.797 us; speedup vs baseline: 2.7710x; 2.7710x over previous
//
#include <hip/hip_runtime.h>

// VQ codebook quantization, MI355X. Two-phase argmin:
//   pass A: bf16 MFMA approximate distances -> per-(row, 64k-window) minima
//   pass B: exact fp32 rescore of flagged windows (reference combine + lowest-k ties)
// B=8192, d_latent=512, ncb=2, K=8192, d_sub=256.

#define KCODES 8192
#define DSUB   256
#define BROWS  8192
#define NROWS  16384

#define QUANT_N  (BROWS * 512)
#define IDX_OFF  QUANT_N
#define LOSS_OFF (QUANT_N + NROWS)

// ws layout (bytes)
#define WS_ESQ    0          // 16384 f32
#define WS_ZSQ    65536      // 16384 f32
#define WS_IDX    131072     // 16384 i32
#define WS_COUNTS 196608     // 16384 i32 (zeroed)
#define WS_LOSS   262144     // 1 f32 (zeroed)
#define WS_ZBF    1048576    // [2][8192][256] bf16 = 8 MB (de-interleaved by codebook)
#define WS_EBF    9437184    // [2][8192][256] bf16 = 8 MB
#define WS_TM     17825792   // [2][128][8192] f32 = 8 MB  (window = 64 codes)
// total 25 MB

#define EPS 2e-4f

typedef __attribute__((ext_vector_type(8))) short short8;
typedef __attribute__((ext_vector_type(4))) float floatx4;

__device__ inline void gl2lds16(const void* g, void* l) {
  __builtin_amdgcn_global_load_lds(
      (const __attribute__((address_space(1))) void*)g,
      (__attribute__((address_space(3))) void*)l, 16, 0, 0);
}

__device__ inline unsigned short f2bf(float f) {
  unsigned u = __float_as_uint(f);
  return (unsigned short)((u + 0x7FFFu + ((u >> 16) & 1u)) >> 16);
}

// ---------------------------------------------------------------- sq kernel
__global__ void sq_kernel(const float* __restrict__ z, const float* __restrict__ e,
                          float* __restrict__ e_sq, float* __restrict__ z_sq) {
  int row  = blockIdx.x * 4 + (threadIdx.x >> 6);
  int lane = threadIdx.x & 63;
  const float* src;
  float* dst;
  int r;
  if (row < NROWS) { r = row;         src = e + (size_t)r * DSUB; dst = e_sq; }
  else             { r = row - NROWS; src = z + (size_t)r * DSUB; dst = z_sq; }
  float4 v = ((const float4*)src)[lane];
  float s = v.x * v.x + v.y * v.y + v.z * v.z + v.w * v.w;
  #pragma unroll
  for (int off = 32; off; off >>= 1) s += __shfl_down(s, off, 64);
  if (lane == 0) dst[r] = s;
}

// ------------------------------------------------------------ convert kernel
// z fp32 [16384][256] -> zb [n][b][256] bf16 (de-interleave rz=2b+n); e straight.
__global__ void convert_kernel(const float* __restrict__ z, const float* __restrict__ e,
                               unsigned short* __restrict__ zb, unsigned short* __restrict__ eb) {
  int g = blockIdx.x * 256 + threadIdx.x;  // float4 group id, 0..2M
  if (g < 1048576) {
    int row = g >> 6, d4 = g & 63;
    float4 v = ((const float4*)(z + (size_t)row * DSUB))[d4];
    int n = row & 1, b = row >> 1;
    ushort4 o;
    o.x = f2bf(v.x); o.y = f2bf(v.y); o.z = f2bf(v.z); o.w = f2bf(v.w);
    *(ushort4*)(zb + (size_t)n * 2097152 + (size_t)b * 256 + d4 * 4) = o;
  } else {
    int ge = g - 1048576;
    float4 v = ((const float4*)e)[ge];
    ushort4 o;
    o.x = f2bf(v.x); o.y = f2bf(v.y); o.z = f2bf(v.z); o.w = f2bf(v.w);
    *(ushort4*)(eb + (size_t)ge * 4) = o;
  }
}

// ------------------------------------------------------------ pass A (MFMA)
// Block: 128 codes (M) x 128 z-rows (N), K=256 over 8 steps of 32.
// Wave w: 64x64 subtile at ((w>>1)*64, (w&1)*64); 4x4 fragments of 16x16x32.
// Output: tm[n][window64][row] = min over 64 codes of (e_sq[k] - 2*z.e)
__global__ __launch_bounds__(256)
void passA_kernel(const unsigned short* __restrict__ zb, const unsigned short* __restrict__ eb,
                  const float* __restrict__ e_sq, float* __restrict__ tm) {
  __shared__ unsigned short As[128 * 32];  // codes x k-chunk
  __shared__ unsigned short Bs[128 * 32];  // z-rows x k-chunk

  const int n     = blockIdx.z;
  const int Mtile = blockIdx.x * 128;
  const int Ntile = blockIdx.y * 128;
  const int tid   = threadIdx.x;
  const int w     = tid >> 6, lane = tid & 63;
  const int quad  = lane >> 4, c16 = lane & 15;

  const unsigned short* ebase = eb + (size_t)n * (KCODES * DSUB);
  const unsigned short* zbase = zb + (size_t)n * (BROWS * DSUB);

  floatx4 acc[4][4];
  #pragma unroll
  for (int i = 0; i < 4; ++i)
    #pragma unroll
    for (int j = 0; j < 4; ++j) acc[i][j] = (floatx4){0.f, 0.f, 0.f, 0.f};

  const int r0 = w * 32 + (lane >> 2);   // staging row (+16 for second inst)
  const int ce = (lane & 3) * 8;         // staging k-elem offset
  const int arow = (w >> 1) * 64, brow = (w & 1) * 64;

  for (int k0 = 0; k0 < DSUB; k0 += 32) {
    if (k0) __syncthreads();
    gl2lds16(ebase + (size_t)(Mtile + r0) * DSUB + k0 + ce,      As + w * 1024);
    gl2lds16(ebase + (size_t)(Mtile + r0 + 16) * DSUB + k0 + ce, As + w * 1024 + 512);
    gl2lds16(zbase + (size_t)(Ntile + r0) * DSUB + k0 + ce,      Bs + w * 1024);
    gl2lds16(zbase + (size_t)(Ntile + r0 + 16) * DSUB + k0 + ce, Bs + w * 1024 + 512);
    __syncthreads();

    short8 a[4], b[4];
    #pragma unroll
    for (int mf = 0; mf < 4; ++mf) a[mf] = *(const short8*)&As[(arow + mf * 16 + c16) * 32 + quad * 8];
    #pragma unroll
    for (int nf = 0; nf < 4; ++nf) b[nf] = *(const short8*)&Bs[(brow + nf * 16 + c16) * 32 + quad * 8];
    #pragma unroll
    for (int mf = 0; mf < 4; ++mf)
      #pragma unroll
      for (int nf = 0; nf < 4; ++nf)
        acc[mf][nf] = __builtin_amdgcn_mfma_f32_16x16x32_bf16(a[mf], b[nf], acc[mf][nf], 0, 0, 0);
  }

  // epilogue: window-min of e_sq[k] - 2*c over the wave's 64 codes, per column
  const float* esq  = e_sq + n * KCODES;
  const int mbase   = Mtile + arow;
  const int nbase   = Ntile + brow;
  float* tmn = tm + (size_t)n * (128 * 8192);

  float eq[4][4];
  #pragma unroll
  for (int mf = 0; mf < 4; ++mf) {
    int kb = mbase + mf * 16 + quad * 4;
    #pragma unroll
    for (int i = 0; i < 4; ++i) eq[mf][i] = esq[kb + i];
  }

  #pragma unroll
  for (int nf = 0; nf < 4; ++nf) {
    float v = 3.4e38f;
    #pragma unroll
    for (int mf = 0; mf < 4; ++mf) {
      v = fminf(v, eq[mf][0] - 2.0f * acc[mf][nf][0]);
      v = fminf(v, eq[mf][1] - 2.0f * acc[mf][nf][1]);
      v = fminf(v, eq[mf][2] - 2.0f * acc[mf][nf][2]);
      v = fminf(v, eq[mf][3] - 2.0f * acc[mf][nf][3]);
    }
    v = fminf(v, __shfl_xor(v, 16, 64));
    v = fminf(v, __shfl_xor(v, 32, 64));
    if (quad == 0)
      tmn[(size_t)(mbase >> 6) * 8192 + nbase + nf * 16 + c16] = v;
  }
}

// ------------------------------------------------------------ pass B (exact)
// One block per row (16384). Flag windows with tm <= min+EPS, rescore exactly
// in fp32 with the reference combine; lowest-k tie-break.
__global__ __launch_bounds__(256)
void passB_kernel(const float* __restrict__ z, const float* __restrict__ emb,
                  const float* __restrict__ e_sq, const float* __restrict__ z_sq,
                  const float* __restrict__ tm, int* __restrict__ out_idx,
                  int* __restrict__ counts) {
  __shared__ float zrow[256];
  __shared__ float red[128];
  __shared__ float part[4][64];
  __shared__ int   cand[128];
  __shared__ int   ncand;

  const int row = blockIdx.x;
  const int n = row & 1, b = row >> 1;
  const int tid = threadIdx.x, w = tid >> 6, lane = tid & 63;

  zrow[tid] = z[(size_t)row * DSUB + tid];
  float myt = 3.4e38f;
  if (tid < 128) { myt = tm[(size_t)n * 1048576 + (size_t)tid * 8192 + b]; red[tid] = myt; }
  if (tid == 0) ncand = 0;
  __syncthreads();
  if (tid < 64) red[tid] = fminf(red[tid], red[tid + 64]);
  __syncthreads();
  if (tid < 64) {
    float v = red[tid];
    #pragma unroll
    for (int off = 32; off; off >>= 1) v = fminf(v, __shfl_down(v, off, 64));
    if (tid == 0) red[0] = v;
  }
  __syncthreads();
  float m = red[0];
  if (tid < 128 && myt <= m + EPS) { int p = atomicAdd(&ncand, 1); cand[p] = tid; }
  __syncthreads();
  const int nc  = ncand;
  const float zsr = z_sq[row];

  float bestd = 3.4e38f;
  int   bestk = 0x7fffffff;
  for (int c = 0; c < nc; ++c) {
    int kg = cand[c] * 64 + lane;
    const float4* er = (const float4*)(emb + ((size_t)n * KCODES + kg) * DSUB + w * 64);
    const float4* zr = (const float4*)zrow + w * 16;
    float s = 0.f;
    #pragma unroll
    for (int j = 0; j < 16; ++j) {
      float4 ev = er[j]; float4 zv = zr[j];
      s += ev.x * zv.x; s += ev.y * zv.y; s += ev.z * zv.z; s += ev.w * zv.w;
    }
    part[w][lane] = s;
    __syncthreads();
    if (tid < 64) {
      float cr = part[0][lane] + part[1][lane] + part[2][lane] + part[3][lane];
      float dist = (zsr - 2.0f * cr) + e_sq[n * KCODES + kg];
      if (dist < bestd || (dist == bestd && kg < bestk)) { bestd = dist; bestk = kg; }
    }
    __syncthreads();
  }
  if (tid < 64) {
    #pragma unroll
    for (int off = 32; off; off >>= 1) {
      float d2 = __shfl_down(bestd, off, 64);
      int   k2 = __shfl_down(bestk, off, 64);
      if (d2 < bestd || (d2 == bestd && k2 < bestk)) { bestd = d2; bestk = k2; }
    }
    if (lane == 0) { out_idx[row] = bestk; atomicAdd(&counts[n * KCODES + bestk], 1); }
  }
}

// ------------------------------------------------------- gather/loss kernel
__global__ void gather_kernel(const float* __restrict__ z, const float* __restrict__ emb,
                              const int* __restrict__ idx, float* __restrict__ out,
                              float* __restrict__ loss) {
  int row  = blockIdx.x * 4 + (threadIdx.x >> 6);
  int lane = threadIdx.x & 63;
  int n = row & 1;
  int k = idx[row];
  float4 ev = ((const float4*)(emb + ((size_t)n * KCODES + k) * DSUB))[lane];
  float4 zv = ((const float4*)(z + (size_t)row * DSUB))[lane];
  ((float4*)out)[(size_t)row * 64 + lane] = ev;
  float dx = zv.x - ev.x, dy = zv.y - ev.y, dz = zv.z - ev.z, dw = zv.w - ev.w;
  float s = dx * dx + dy * dy + dz * dz + dw * dw;
  #pragma unroll
  for (int off = 32; off; off >>= 1) s += __shfl_down(s, off, 64);
  if (lane == 0) {
    atomicAdd(loss, s);
    out[IDX_OFF + row] = (float)k;
  }
}

// ------------------------------------------------------------ final kernel
__global__ void final_kernel(const int* __restrict__ counts, const float* __restrict__ loss,
                             float* __restrict__ out) {
  __shared__ float red[256];
  float h = 0.0f;
  for (int k = threadIdx.x; k < KCODES; k += 256) {
    float p = (float)(counts[k] + counts[KCODES + k]) * (1.0f / 16384.0f);
    h -= p * logf(p + 1e-10f);
  }
  red[threadIdx.x] = h;
  __syncthreads();
  for (int s = 128; s; s >>= 1) {
    if (threadIdx.x < s) red[threadIdx.x] += red[threadIdx.x + s];
    __syncthreads();
  }
  if (threadIdx.x == 0) {
    out[LOSS_OFF + 0] = 0.25f * loss[0] * (1.0f / (float)QUANT_N);
    out[LOSS_OFF + 1] = 0.0f;
    out[LOSS_OFF + 2] = expf(red[0]);
  }
}

extern "C" void kernel_launch(void* const* d_in, const int* in_sizes, int n_in,
                              void* d_out, int out_size, void* d_ws, size_t ws_size,
                              hipStream_t stream) {
  const float* z   = (const float*)d_in[0];
  const float* emb = (const float*)d_in[1];
  float* out = (float*)d_out;
  char*  ws  = (char*)d_ws;

  float* e_sq   = (float*)(ws + WS_ESQ);
  float* z_sq   = (float*)(ws + WS_ZSQ);
  int*   idx    = (int*)(ws + WS_IDX);
  int*   counts = (int*)(ws + WS_COUNTS);
  float* loss   = (float*)(ws + WS_LOSS);
  unsigned short* zb = (unsigned short*)(ws + WS_ZBF);
  unsigned short* eb = (unsigned short*)(ws + WS_EBF);
  float* tmbuf  = (float*)(ws + WS_TM);

  hipMemsetAsync(ws + WS_COUNTS, 0, 65536 + 16, stream);
  sq_kernel<<<8192, 256, 0, stream>>>(z, emb, e_sq, z_sq);
  convert_kernel<<<8192, 256, 0, stream>>>(z, emb, zb, eb);
  dim3 gA(64, 64, 2);
  passA_kernel<<<gA, 256, 0, stream>>>(zb, eb, e_sq, tmbuf);
  passB_kernel<<<16384, 256, 0, stream>>>(z, emb, e_sq, z_sq, tmbuf, idx, counts);
  gather_kernel<<<4096, 256, 0, stream>>>(z, emb, idx, out, loss);
  final_kernel<<<1, 256, 0, stream>>>(counts, loss, out);
}

// Round 3
// 437.189 us; speedup vs baseline: 3.9475x; 1.4245x over previous
//
#include <hip/hip_runtime.h>

// VQ codebook quantization, MI355X. Two-phase argmin:
//   pass A: bf16 MFMA approximate distances -> per-(row, 64k-window) minima
//   pass B: exact fp32 rescore of flagged windows (reference combine + lowest-k
//           ties), fused with quantized-gather + commitment-loss.
// B=8192, d_latent=512, ncb=2, K=8192, d_sub=256.

#define KCODES 8192
#define DSUB   256
#define BROWS  8192
#define NROWS  16384

#define QUANT_N  (BROWS * 512)
#define IDX_OFF  QUANT_N
#define LOSS_OFF (QUANT_N + NROWS)

// ws layout (bytes)
#define WS_ESQ    0          // 16384 f32
#define WS_ZSQ    65536      // 16384 f32
#define WS_COUNTS 196608     // 16384 i32 (zeroed)
#define WS_LOSS   262144     // 1 f32 (zeroed)
#define WS_ZBF    1048576    // [2][8192][256] bf16 = 8 MB (de-interleaved by codebook)
#define WS_EBF    9437184    // [2][8192][256] bf16 = 8 MB
#define WS_TM     17825792   // [2][128][8192] f32 = 8 MB  (window = 64 codes)
// total 25 MB

#define EPS 2e-4f

typedef __attribute__((ext_vector_type(8))) short short8;
typedef __attribute__((ext_vector_type(4))) float floatx4;

__device__ inline void gl2lds16(const void* g, void* l) {
  __builtin_amdgcn_global_load_lds(
      (const __attribute__((address_space(1))) void*)g,
      (__attribute__((address_space(3))) void*)l, 16, 0, 0);
}

__device__ inline unsigned short f2bf(float f) {
  unsigned u = __float_as_uint(f);
  return (unsigned short)((u + 0x7FFFu + ((u >> 16) & 1u)) >> 16);
}

// ------------------------------------------------------------ prep kernel
// One wave per row over both arrays (32768 rows):
//   rows [0, NROWS)       : embedding row r -> e_sq[r], eb[r]
//   rows [NROWS, 2*NROWS) : z row r -> z_sq[r], zb de-interleaved [n][b][256]
__global__ void prep_kernel(const float* __restrict__ z, const float* __restrict__ e,
                            float* __restrict__ e_sq, float* __restrict__ z_sq,
                            unsigned short* __restrict__ zb, unsigned short* __restrict__ eb) {
  int row  = blockIdx.x * 4 + (threadIdx.x >> 6);
  int lane = threadIdx.x & 63;
  float4 v;
  if (row < NROWS) {
    v = ((const float4*)(e + (size_t)row * DSUB))[lane];
    ushort4 o;
    o.x = f2bf(v.x); o.y = f2bf(v.y); o.z = f2bf(v.z); o.w = f2bf(v.w);
    *(ushort4*)(eb + (size_t)row * DSUB + lane * 4) = o;
    float s = v.x * v.x + v.y * v.y + v.z * v.z + v.w * v.w;
    #pragma unroll
    for (int off = 32; off; off >>= 1) s += __shfl_down(s, off, 64);
    if (lane == 0) e_sq[row] = s;
  } else {
    int r = row - NROWS;
    v = ((const float4*)(z + (size_t)r * DSUB))[lane];
    int n = r & 1, b = r >> 1;
    ushort4 o;
    o.x = f2bf(v.x); o.y = f2bf(v.y); o.z = f2bf(v.z); o.w = f2bf(v.w);
    *(ushort4*)(zb + (size_t)n * 2097152 + (size_t)b * DSUB + lane * 4) = o;
    float s = v.x * v.x + v.y * v.y + v.z * v.z + v.w * v.w;
    #pragma unroll
    for (int off = 32; off; off >>= 1) s += __shfl_down(s, off, 64);
    if (lane == 0) z_sq[r] = s;
  }
}

// ------------------------------------------------------------ pass A (MFMA)
// Block: 128 codes (M) x 128 z-rows (N), K=256 over 8 steps of 32.
// Wave w: 64x64 subtile at ((w>>1)*64, (w&1)*64); 4x4 fragments of 16x16x32.
// Output: tm[n][window64][row] = min over 64 codes of (e_sq[k] - 2*z.e)
__global__ __launch_bounds__(256)
void passA_kernel(const unsigned short* __restrict__ zb, const unsigned short* __restrict__ eb,
                  const float* __restrict__ e_sq, float* __restrict__ tm) {
  __shared__ unsigned short As[128 * 32];  // codes x k-chunk
  __shared__ unsigned short Bs[128 * 32];  // z-rows x k-chunk

  const int n     = blockIdx.z;
  const int Mtile = blockIdx.x * 128;
  const int Ntile = blockIdx.y * 128;
  const int tid   = threadIdx.x;
  const int w     = tid >> 6, lane = tid & 63;
  const int quad  = lane >> 4, c16 = lane & 15;

  const unsigned short* ebase = eb + (size_t)n * (KCODES * DSUB);
  const unsigned short* zbase = zb + (size_t)n * (BROWS * DSUB);

  floatx4 acc[4][4];
  #pragma unroll
  for (int i = 0; i < 4; ++i)
    #pragma unroll
    for (int j = 0; j < 4; ++j) acc[i][j] = (floatx4){0.f, 0.f, 0.f, 0.f};

  const int r0 = w * 32 + (lane >> 2);   // staging row (+16 for second inst)
  const int ce = (lane & 3) * 8;         // staging k-elem offset
  const int arow = (w >> 1) * 64, brow = (w & 1) * 64;

  for (int k0 = 0; k0 < DSUB; k0 += 32) {
    if (k0) __syncthreads();
    gl2lds16(ebase + (size_t)(Mtile + r0) * DSUB + k0 + ce,      As + w * 1024);
    gl2lds16(ebase + (size_t)(Mtile + r0 + 16) * DSUB + k0 + ce, As + w * 1024 + 512);
    gl2lds16(zbase + (size_t)(Ntile + r0) * DSUB + k0 + ce,      Bs + w * 1024);
    gl2lds16(zbase + (size_t)(Ntile + r0 + 16) * DSUB + k0 + ce, Bs + w * 1024 + 512);
    __syncthreads();

    short8 a[4], b[4];
    #pragma unroll
    for (int mf = 0; mf < 4; ++mf) a[mf] = *(const short8*)&As[(arow + mf * 16 + c16) * 32 + quad * 8];
    #pragma unroll
    for (int nf = 0; nf < 4; ++nf) b[nf] = *(const short8*)&Bs[(brow + nf * 16 + c16) * 32 + quad * 8];
    #pragma unroll
    for (int mf = 0; mf < 4; ++mf)
      #pragma unroll
      for (int nf = 0; nf < 4; ++nf)
        acc[mf][nf] = __builtin_amdgcn_mfma_f32_16x16x32_bf16(a[mf], b[nf], acc[mf][nf], 0, 0, 0);
  }

  // epilogue: window-min of e_sq[k] - 2*c over the wave's 64 codes, per column
  const float* esq  = e_sq + n * KCODES;
  const int mbase   = Mtile + arow;
  const int nbase   = Ntile + brow;
  float* tmn = tm + (size_t)n * (128 * 8192);

  float eq[4][4];
  #pragma unroll
  for (int mf = 0; mf < 4; ++mf) {
    int kb = mbase + mf * 16 + quad * 4;
    #pragma unroll
    for (int i = 0; i < 4; ++i) eq[mf][i] = esq[kb + i];
  }

  #pragma unroll
  for (int nf = 0; nf < 4; ++nf) {
    float v = 3.4e38f;
    #pragma unroll
    for (int mf = 0; mf < 4; ++mf) {
      v = fminf(v, eq[mf][0] - 2.0f * acc[mf][nf][0]);
      v = fminf(v, eq[mf][1] - 2.0f * acc[mf][nf][1]);
      v = fminf(v, eq[mf][2] - 2.0f * acc[mf][nf][2]);
      v = fminf(v, eq[mf][3] - 2.0f * acc[mf][nf][3]);
    }
    v = fminf(v, __shfl_xor(v, 16, 64));
    v = fminf(v, __shfl_xor(v, 32, 64));
    if (quad == 0)
      tmn[(size_t)(mbase >> 6) * 8192 + nbase + nf * 16 + c16] = v;
  }
}

// ------------------------------------------------------------ pass B (exact + gather)
// One block per row (16384). Flag windows with tm <= min+EPS, rescore exactly
// in fp32 with the reference combine; lowest-k tie-break. Coalesced: wave=code,
// lane=d-chunk. Then write quantized row + index + loss partial.
__global__ __launch_bounds__(256)
void passB_kernel(const float* __restrict__ z, const float* __restrict__ emb,
                  const float* __restrict__ e_sq, const float* __restrict__ z_sq,
                  const float* __restrict__ tm, float* __restrict__ out,
                  int* __restrict__ counts, float* __restrict__ loss) {
  __shared__ float zrow[256];
  __shared__ float red[128];
  __shared__ int   cand[128];
  __shared__ int   ncand;
  __shared__ float wbest[4];
  __shared__ int   wbidx[4];

  const int row = blockIdx.x;
  const int n = row & 1, b = row >> 1;
  const int tid = threadIdx.x, w = tid >> 6, lane = tid & 63;

  zrow[tid] = z[(size_t)row * DSUB + tid];
  float myt = 3.4e38f;
  if (tid < 128) { myt = tm[(size_t)n * 1048576 + (size_t)tid * 8192 + b]; red[tid] = myt; }
  if (tid == 0) ncand = 0;
  __syncthreads();
  if (tid < 64) red[tid] = fminf(red[tid], red[tid + 64]);
  __syncthreads();
  if (tid < 64) {
    float v = red[tid];
    #pragma unroll
    for (int off = 32; off; off >>= 1) v = fminf(v, __shfl_down(v, off, 64));
    if (tid == 0) red[0] = v;
  }
  __syncthreads();
  float m = red[0];
  if (tid < 128 && myt <= m + EPS) { int p = atomicAdd(&ncand, 1); cand[p] = tid; }
  __syncthreads();
  const int nc = ncand;
  const float zsr = z_sq[row];
  const float4 zv = *(const float4*)&zrow[lane * 4];
  const float* ebase = emb + (size_t)n * KCODES * DSUB;
  const float* esq   = e_sq + n * KCODES;

  float bestd = 3.4e38f;
  int   bestk = 0x7fffffff;
  for (int c = 0; c < nc; ++c) {
    const int kb = cand[c] * 64 + w * 16;  // this wave's 16 codes
    #pragma unroll
    for (int j = 0; j < 16; ++j) {
      const int k = kb + j;
      float4 ev = ((const float4*)(ebase + (size_t)k * DSUB))[lane];
      float s = ev.x * zv.x + ev.y * zv.y + ev.z * zv.z + ev.w * zv.w;
      #pragma unroll
      for (int off = 32; off; off >>= 1) s += __shfl_xor(s, off, 64);
      float dist = (zsr - 2.0f * s) + esq[k];
      if (dist < bestd || (dist == bestd && k < bestk)) { bestd = dist; bestk = k; }
    }
  }
  if (lane == 0) { wbest[w] = bestd; wbidx[w] = bestk; }
  __syncthreads();
  if (tid == 0) {
    float bd = wbest[0]; int bk = wbidx[0];
    #pragma unroll
    for (int i = 1; i < 4; ++i)
      if (wbest[i] < bd || (wbest[i] == bd && wbidx[i] < bk)) { bd = wbest[i]; bk = wbidx[i]; }
    wbidx[0] = bk;
    out[IDX_OFF + row] = (float)bk;
    atomicAdd(&counts[n * KCODES + bk], 1);
  }
  __syncthreads();
  const int bk = wbidx[0];

  // gather quantized row + commitment loss partial
  float evs = ebase[(size_t)bk * DSUB + tid];
  float zvs = zrow[tid];
  out[(size_t)row * DSUB + tid] = evs;   // row*256 == b*512 + n*256
  float d = zvs - evs;
  d = d * d;
  #pragma unroll
  for (int off = 32; off; off >>= 1) d += __shfl_down(d, off, 64);
  if (lane == 0) red[w] = d;
  __syncthreads();
  if (tid == 0) atomicAdd(loss, red[0] + red[1] + red[2] + red[3]);
}

// ------------------------------------------------------------ final kernel
__global__ void final_kernel(const int* __restrict__ counts, const float* __restrict__ loss,
                             float* __restrict__ out) {
  __shared__ float red[256];
  float h = 0.0f;
  for (int k = threadIdx.x; k < KCODES; k += 256) {
    float p = (float)(counts[k] + counts[KCODES + k]) * (1.0f / 16384.0f);
    h -= p * logf(p + 1e-10f);
  }
  red[threadIdx.x] = h;
  __syncthreads();
  for (int s = 128; s; s >>= 1) {
    if (threadIdx.x < s) red[threadIdx.x] += red[threadIdx.x + s];
    __syncthreads();
  }
  if (threadIdx.x == 0) {
    out[LOSS_OFF + 0] = 0.25f * loss[0] * (1.0f / (float)QUANT_N);
    out[LOSS_OFF + 1] = 0.0f;
    out[LOSS_OFF + 2] = expf(red[0]);
  }
}

extern "C" void kernel_launch(void* const* d_in, const int* in_sizes, int n_in,
                              void* d_out, int out_size, void* d_ws, size_t ws_size,
                              hipStream_t stream) {
  const float* z   = (const float*)d_in[0];
  const float* emb = (const float*)d_in[1];
  float* out = (float*)d_out;
  char*  ws  = (char*)d_ws;

  float* e_sq   = (float*)(ws + WS_ESQ);
  float* z_sq   = (float*)(ws + WS_ZSQ);
  int*   counts = (int*)(ws + WS_COUNTS);
  float* loss   = (float*)(ws + WS_LOSS);
  unsigned short* zb = (unsigned short*)(ws + WS_ZBF);
  unsigned short* eb = (unsigned short*)(ws + WS_EBF);
  float* tmbuf  = (float*)(ws + WS_TM);

  hipMemsetAsync(ws + WS_COUNTS, 0, 65536 + 16, stream);
  prep_kernel<<<8192, 256, 0, stream>>>(z, emb, e_sq, z_sq, zb, eb);
  dim3 gA(64, 64, 2);
  passA_kernel<<<gA, 256, 0, stream>>>(zb, eb, e_sq, tmbuf);
  passB_kernel<<<16384, 256, 0, stream>>>(z, emb, e_sq, z_sq, tmbuf, out, counts, loss);
  final_kernel<<<1, 256, 0, stream>>>(counts, loss, out);
}

// Round 4
// 403.531 us; speedup vs baseline: 4.2767x; 1.0834x over previous
//
#include <hip/hip_runtime.h>
#include <hip/hip_fp16.h>

// VQ codebook quantization, MI355X. Two-phase argmin:
//   pass A: bf16 MFMA approximate distances -> per-(row, 16-code-window) minima
//           (fp16, transposed layout tm[n][row][512])
//   pass B: exact fp32 rescore of flagged windows (reference combine + lowest-k
//           ties), fused with quantized-gather + commitment-loss.
// B=8192, d_latent=512, ncb=2, K=8192, d_sub=256.

#define KCODES 8192
#define DSUB   256
#define BROWS  8192
#define NROWS  16384
#define NWIN   512            // 16-code windows per codebook

#define QUANT_N  (BROWS * 512)
#define IDX_OFF  QUANT_N
#define LOSS_OFF (QUANT_N + NROWS)

// ws layout (bytes)
#define WS_ESQ    0          // 16384 f32
#define WS_ZSQ    65536      // 16384 f32
#define WS_COUNTS 196608     // 16384 i32 (zeroed)
#define WS_LOSS   262144     // 1 f32 (zeroed)
#define WS_ZBF    1048576    // [2][8192][256] bf16 = 8 MB (de-interleaved by codebook)
#define WS_EBF    9437184    // [2][8192][256] bf16 = 8 MB
#define WS_TM     17825792   // [2][8192][512] fp16 = 16 MB (window = 16 codes)
// total ~33 MB

#define EPS 2.5e-4f

typedef __attribute__((ext_vector_type(8))) short short8;
typedef __attribute__((ext_vector_type(4))) float floatx4;

__device__ inline void gl2lds16(const void* g, void* l) {
  __builtin_amdgcn_global_load_lds(
      (const __attribute__((address_space(1))) void*)g,
      (__attribute__((address_space(3))) void*)l, 16, 0, 0);
}

__device__ inline unsigned short f2bf(float f) {
  unsigned u = __float_as_uint(f);
  return (unsigned short)((u + 0x7FFFu + ((u >> 16) & 1u)) >> 16);
}

// ------------------------------------------------------------ prep kernel
__global__ void prep_kernel(const float* __restrict__ z, const float* __restrict__ e,
                            float* __restrict__ e_sq, float* __restrict__ z_sq,
                            unsigned short* __restrict__ zb, unsigned short* __restrict__ eb) {
  int row  = blockIdx.x * 4 + (threadIdx.x >> 6);
  int lane = threadIdx.x & 63;
  float4 v;
  if (row < NROWS) {
    v = ((const float4*)(e + (size_t)row * DSUB))[lane];
    ushort4 o;
    o.x = f2bf(v.x); o.y = f2bf(v.y); o.z = f2bf(v.z); o.w = f2bf(v.w);
    *(ushort4*)(eb + (size_t)row * DSUB + lane * 4) = o;
    float s = v.x * v.x + v.y * v.y + v.z * v.z + v.w * v.w;
    #pragma unroll
    for (int off = 32; off; off >>= 1) s += __shfl_down(s, off, 64);
    if (lane == 0) e_sq[row] = s;
  } else {
    int r = row - NROWS;
    v = ((const float4*)(z + (size_t)r * DSUB))[lane];
    int n = r & 1, b = r >> 1;
    ushort4 o;
    o.x = f2bf(v.x); o.y = f2bf(v.y); o.z = f2bf(v.z); o.w = f2bf(v.w);
    *(ushort4*)(zb + (size_t)n * 2097152 + (size_t)b * DSUB + lane * 4) = o;
    float s = v.x * v.x + v.y * v.y + v.z * v.z + v.w * v.w;
    #pragma unroll
    for (int off = 32; off; off >>= 1) s += __shfl_down(s, off, 64);
    if (lane == 0) z_sq[r] = s;
  }
}

// ------------------------------------------------------------ pass A (MFMA)
// Block: 128 codes (M) x 128 z-rows (N), K=256 over 8 steps of 32.
// Wave w: 64x64 subtile at ((w>>1)*64, (w&1)*64); 4x4 fragments of 16x16x32.
// Output: tm[n][row][win] = min over window's 16 codes of (e_sq[k] - 2*z.e), fp16.
__global__ __launch_bounds__(256)
void passA_kernel(const unsigned short* __restrict__ zb, const unsigned short* __restrict__ eb,
                  const float* __restrict__ e_sq, __half* __restrict__ tm) {
  __shared__ unsigned short As[128 * 32];  // codes x k-chunk
  __shared__ unsigned short Bs[128 * 32];  // z-rows x k-chunk

  const int n     = blockIdx.z;
  const int Mtile = blockIdx.x * 128;
  const int Ntile = blockIdx.y * 128;
  const int tid   = threadIdx.x;
  const int w     = tid >> 6, lane = tid & 63;
  const int quad  = lane >> 4, c16 = lane & 15;

  const unsigned short* ebase = eb + (size_t)n * (KCODES * DSUB);
  const unsigned short* zbase = zb + (size_t)n * (BROWS * DSUB);

  floatx4 acc[4][4];
  #pragma unroll
  for (int i = 0; i < 4; ++i)
    #pragma unroll
    for (int j = 0; j < 4; ++j) acc[i][j] = (floatx4){0.f, 0.f, 0.f, 0.f};

  const int r0 = w * 32 + (lane >> 2);   // staging row (+16 for second inst)
  const int ce = (lane & 3) * 8;         // staging k-elem offset
  const int arow = (w >> 1) * 64, brow = (w & 1) * 64;

  for (int k0 = 0; k0 < DSUB; k0 += 32) {
    if (k0) __syncthreads();
    gl2lds16(ebase + (size_t)(Mtile + r0) * DSUB + k0 + ce,      As + w * 1024);
    gl2lds16(ebase + (size_t)(Mtile + r0 + 16) * DSUB + k0 + ce, As + w * 1024 + 512);
    gl2lds16(zbase + (size_t)(Ntile + r0) * DSUB + k0 + ce,      Bs + w * 1024);
    gl2lds16(zbase + (size_t)(Ntile + r0 + 16) * DSUB + k0 + ce, Bs + w * 1024 + 512);
    __syncthreads();

    short8 a[4], b[4];
    #pragma unroll
    for (int mf = 0; mf < 4; ++mf) a[mf] = *(const short8*)&As[(arow + mf * 16 + c16) * 32 + quad * 8];
    #pragma unroll
    for (int nf = 0; nf < 4; ++nf) b[nf] = *(const short8*)&Bs[(brow + nf * 16 + c16) * 32 + quad * 8];
    #pragma unroll
    for (int mf = 0; mf < 4; ++mf)
      #pragma unroll
      for (int nf = 0; nf < 4; ++nf)
        acc[mf][nf] = __builtin_amdgcn_mfma_f32_16x16x32_bf16(a[mf], b[nf], acc[mf][nf], 0, 0, 0);
  }

  // epilogue: per-mf (16-code window) min of e_sq[k] - 2*c, per z-row column
  const float* esq  = e_sq + n * KCODES;
  const int mbase   = Mtile + arow;
  const int nbase   = Ntile + brow;
  __half* tmn = tm + (size_t)n * (BROWS * NWIN);

  float eq[4][4];
  #pragma unroll
  for (int mf = 0; mf < 4; ++mf) {
    int kb = mbase + mf * 16 + quad * 4;
    #pragma unroll
    for (int i = 0; i < 4; ++i) eq[mf][i] = esq[kb + i];
  }

  #pragma unroll
  for (int nf = 0; nf < 4; ++nf) {
    float vm[4];
    #pragma unroll
    for (int mf = 0; mf < 4; ++mf) {
      float v = eq[mf][0] - 2.0f * acc[mf][nf][0];
      v = fminf(v, eq[mf][1] - 2.0f * acc[mf][nf][1]);
      v = fminf(v, eq[mf][2] - 2.0f * acc[mf][nf][2]);
      v = fminf(v, eq[mf][3] - 2.0f * acc[mf][nf][3]);
      v = fminf(v, __shfl_xor(v, 16, 64));
      v = fminf(v, __shfl_xor(v, 32, 64));
      vm[mf] = v;
    }
    if (quad == 0) {
      int zr = nbase + nf * 16 + c16;
      ushort4 o;
      o.x = __half_as_ushort(__float2half(vm[0]));
      o.y = __half_as_ushort(__float2half(vm[1]));
      o.z = __half_as_ushort(__float2half(vm[2]));
      o.w = __half_as_ushort(__float2half(vm[3]));
      *(ushort4*)&tmn[(size_t)zr * NWIN + (mbase >> 4)] = o;
    }
  }
}

// ------------------------------------------------------------ pass B (exact + gather)
// One block per row (16384). Flag 16-code windows with tm <= min+EPS (bitmask),
// rescore exactly in fp32 with the reference combine; lowest-k tie-break.
// Then write quantized row + index + loss partial.
__global__ __launch_bounds__(256)
void passB_kernel(const float* __restrict__ z, const float* __restrict__ emb,
                  const float* __restrict__ e_sq, const float* __restrict__ z_sq,
                  const __half* __restrict__ tm, float* __restrict__ out,
                  int* __restrict__ counts, float* __restrict__ loss) {
  __shared__ float    zrow[256];
  __shared__ unsigned mask[16];
  __shared__ float    wred[4];
  __shared__ float    wbest[4];
  __shared__ int      wbidx[4];
  __shared__ int      bksh;

  const int row = blockIdx.x;           // rz = b*2 + n
  const int n = row & 1, b = row >> 1;
  const int tid = threadIdx.x, w = tid >> 6, lane = tid & 63;

  zrow[tid] = z[(size_t)row * DSUB + tid];
  if (tid < 16) mask[tid] = 0;

  const __half* tmr = tm + ((size_t)n * BROWS + b) * NWIN;
  ushort2 tq = *(const ushort2*)&tmr[tid * 2];
  float t0 = __half2float(__ushort_as_half(tq.x));
  float t1 = __half2float(__ushort_as_half(tq.y));
  float mv = fminf(t0, t1);
  #pragma unroll
  for (int off = 32; off; off >>= 1) mv = fminf(mv, __shfl_xor(mv, off, 64));
  if (lane == 0) wred[w] = mv;
  __syncthreads();
  const float m   = fminf(fminf(wred[0], wred[1]), fminf(wred[2], wred[3]));
  const float thr = m + EPS;
  unsigned bits = (t0 <= thr ? 1u : 0u) | (t1 <= thr ? 2u : 0u);
  if (bits) atomicOr(&mask[tid >> 4], bits << ((tid & 15) * 2));
  __syncthreads();

  const float zsr = z_sq[row];
  const float4 zv = *(const float4*)&zrow[lane * 4];
  const float* ebase = emb + (size_t)n * KCODES * DSUB;
  const float* esq   = e_sq + n * KCODES;

  float bestd = 3.4e38f;
  int   bestk = 0x7fffffff;
  for (int word = 0; word < 16; ++word) {
    unsigned mb = mask[word];
    while (mb) {
      int bit = __ffs(mb) - 1;
      mb &= mb - 1;
      int win = word * 32 + bit;
      int kb  = win * 16 + w * 4;       // this wave's 4 codes of the window
      #pragma unroll
      for (int j = 0; j < 4; ++j) {
        int k = kb + j;
        float4 ev = ((const float4*)(ebase + (size_t)k * DSUB))[lane];
        float s = ev.x * zv.x + ev.y * zv.y + ev.z * zv.z + ev.w * zv.w;
        #pragma unroll
        for (int off = 32; off; off >>= 1) s += __shfl_xor(s, off, 64);
        float dist = (zsr - 2.0f * s) + esq[k];
        if (dist < bestd || (dist == bestd && k < bestk)) { bestd = dist; bestk = k; }
      }
    }
  }
  if (lane == 0) { wbest[w] = bestd; wbidx[w] = bestk; }
  __syncthreads();
  if (tid == 0) {
    float bd = wbest[0]; int bk = wbidx[0];
    #pragma unroll
    for (int i = 1; i < 4; ++i)
      if (wbest[i] < bd || (wbest[i] == bd && wbidx[i] < bk)) { bd = wbest[i]; bk = wbidx[i]; }
    bksh = bk;
    out[IDX_OFF + row] = (float)bk;
    atomicAdd(&counts[n * KCODES + bk], 1);
  }
  __syncthreads();
  const int bk = bksh;

  // gather quantized row + commitment loss partial
  float evs = ebase[(size_t)bk * DSUB + tid];
  float zvs = zrow[tid];
  out[(size_t)row * DSUB + tid] = evs;   // row*256 == b*512 + n*256
  float d = zvs - evs;
  d = d * d;
  #pragma unroll
  for (int off = 32; off; off >>= 1) d += __shfl_down(d, off, 64);
  if (lane == 0) wred[w] = d;
  __syncthreads();
  if (tid == 0) atomicAdd(loss, wred[0] + wred[1] + wred[2] + wred[3]);
}

// ------------------------------------------------------------ final kernel
__global__ void final_kernel(const int* __restrict__ counts, const float* __restrict__ loss,
                             float* __restrict__ out) {
  __shared__ float red[256];
  float h = 0.0f;
  for (int k = threadIdx.x; k < KCODES; k += 256) {
    float p = (float)(counts[k] + counts[KCODES + k]) * (1.0f / 16384.0f);
    h -= p * logf(p + 1e-10f);
  }
  red[threadIdx.x] = h;
  __syncthreads();
  for (int s = 128; s; s >>= 1) {
    if (threadIdx.x < s) red[threadIdx.x] += red[threadIdx.x + s];
    __syncthreads();
  }
  if (threadIdx.x == 0) {
    out[LOSS_OFF + 0] = 0.25f * loss[0] * (1.0f / (float)QUANT_N);
    out[LOSS_OFF + 1] = 0.0f;
    out[LOSS_OFF + 2] = expf(red[0]);
  }
}

extern "C" void kernel_launch(void* const* d_in, const int* in_sizes, int n_in,
                              void* d_out, int out_size, void* d_ws, size_t ws_size,
                              hipStream_t stream) {
  const float* z   = (const float*)d_in[0];
  const float* emb = (const float*)d_in[1];
  float* out = (float*)d_out;
  char*  ws  = (char*)d_ws;

  float* e_sq   = (float*)(ws + WS_ESQ);
  float* z_sq   = (float*)(ws + WS_ZSQ);
  int*   counts = (int*)(ws + WS_COUNTS);
  float* loss   = (float*)(ws + WS_LOSS);
  unsigned short* zb = (unsigned short*)(ws + WS_ZBF);
  unsigned short* eb = (unsigned short*)(ws + WS_EBF);
  __half* tmbuf = (__half*)(ws + WS_TM);

  hipMemsetAsync(ws + WS_COUNTS, 0, 65536 + 16, stream);
  prep_kernel<<<8192, 256, 0, stream>>>(z, emb, e_sq, z_sq, zb, eb);
  dim3 gA(64, 64, 2);
  passA_kernel<<<gA, 256, 0, stream>>>(zb, eb, e_sq, tmbuf);
  passB_kernel<<<16384, 256, 0, stream>>>(z, emb, e_sq, z_sq, tmbuf, out, counts, loss);
  final_kernel<<<1, 256, 0, stream>>>(counts, loss, out);
}

// Round 5
// 321.464 us; speedup vs baseline: 5.3685x; 1.2553x over previous
//
#include <hip/hip_runtime.h>
#include <hip/hip_fp16.h>

// VQ codebook quantization, MI355X. Two-phase argmin:
//   pass A: bf16 MFMA approximate distances -> per-(row, 16-code-window) minima
//           (fp16, transposed layout tm[n][row][512])
//   pass B: wave-per-row exact fp32 rescore of flagged windows (reference
//           combine + lowest-k ties), fused gather + commitment loss.
// All kernels sized to respect the measured ~80 wg/us dispatch ceiling.
// B=8192, d_latent=512, ncb=2, K=8192, d_sub=256.

#define KCODES 8192
#define DSUB   256
#define BROWS  8192
#define NROWS  16384
#define NWIN   512            // 16-code windows per codebook

#define QUANT_N  (BROWS * 512)
#define IDX_OFF  QUANT_N
#define LOSS_OFF (QUANT_N + NROWS)

// ws layout (bytes)
#define WS_ESQ    0          // 16384 f32
#define WS_ZSQ    65536      // 16384 f32
#define WS_COUNTS 196608     // 16384 i32 (zeroed)
#define WS_LOSS   262144     // 1 f32 (zeroed)
#define WS_ZBF    1048576    // [2][8192][256] bf16 = 8 MB (de-interleaved by codebook)
#define WS_EBF    9437184    // [2][8192][256] bf16 = 8 MB
#define WS_TM     17825792   // [2][8192][512] fp16 = 16 MB (window = 16 codes)

#define EPS 2.5e-4f

typedef __attribute__((ext_vector_type(8))) short short8;
typedef __attribute__((ext_vector_type(4))) float floatx4;

__device__ inline void gl2lds16(const void* g, void* l) {
  __builtin_amdgcn_global_load_lds(
      (const __attribute__((address_space(1))) void*)g,
      (__attribute__((address_space(3))) void*)l, 16, 0, 0);
}

__device__ inline unsigned short f2bf(float f) {
  unsigned u = __float_as_uint(f);
  return (unsigned short)((u + 0x7FFFu + ((u >> 16) & 1u)) >> 16);
}

// ------------------------------------------------------------ prep kernel
// 1024 blocks x 256; each wave converts 8 rows (emb rows then z rows).
__global__ void prep_kernel(const float* __restrict__ z, const float* __restrict__ e,
                            float* __restrict__ e_sq, float* __restrict__ z_sq,
                            unsigned short* __restrict__ zb, unsigned short* __restrict__ eb) {
  int gw   = blockIdx.x * 4 + (threadIdx.x >> 6);  // 0..4095
  int lane = threadIdx.x & 63;
  for (int i = 0; i < 8; ++i) {
    int row = gw + 4096 * i;                       // 0..32767
    float4 v;
    if (row < NROWS) {
      v = ((const float4*)(e + (size_t)row * DSUB))[lane];
      ushort4 o;
      o.x = f2bf(v.x); o.y = f2bf(v.y); o.z = f2bf(v.z); o.w = f2bf(v.w);
      *(ushort4*)(eb + (size_t)row * DSUB + lane * 4) = o;
      float s = v.x * v.x + v.y * v.y + v.z * v.z + v.w * v.w;
      #pragma unroll
      for (int off = 32; off; off >>= 1) s += __shfl_down(s, off, 64);
      if (lane == 0) e_sq[row] = s;
    } else {
      int r = row - NROWS;
      v = ((const float4*)(z + (size_t)r * DSUB))[lane];
      int n = r & 1, b = r >> 1;
      ushort4 o;
      o.x = f2bf(v.x); o.y = f2bf(v.y); o.z = f2bf(v.z); o.w = f2bf(v.w);
      *(ushort4*)(zb + (size_t)n * 2097152 + (size_t)b * DSUB + lane * 4) = o;
      float s = v.x * v.x + v.y * v.y + v.z * v.z + v.w * v.w;
      #pragma unroll
      for (int off = 32; off; off >>= 1) s += __shfl_down(s, off, 64);
      if (lane == 0) z_sq[r] = s;
    }
  }
}

// ------------------------------------------------------------ pass A (MFMA)
// Block: 128 codes (M) x 4 consecutive 128-row N-tiles, K=256 over 8 steps.
// Wave w: 64x64 subtile; 4x4 fragments of 16x16x32.
// Output: tm[n][row][win] = min over window's 16 codes of (e_sq[k] - 2*z.e), fp16.
__global__ __launch_bounds__(256)
void passA_kernel(const unsigned short* __restrict__ zb, const unsigned short* __restrict__ eb,
                  const float* __restrict__ e_sq, __half* __restrict__ tm) {
  __shared__ unsigned short As[128 * 32];  // codes x k-chunk
  __shared__ unsigned short Bs[128 * 32];  // z-rows x k-chunk

  const int n     = blockIdx.z;
  const int Mtile = blockIdx.x * 128;
  const int tid   = threadIdx.x;
  const int w     = tid >> 6, lane = tid & 63;
  const int quad  = lane >> 4, c16 = lane & 15;

  const unsigned short* ebase = eb + (size_t)n * (KCODES * DSUB);
  const unsigned short* zbase = zb + (size_t)n * (BROWS * DSUB);

  const int r0 = w * 32 + (lane >> 2);   // staging row (+16 for second inst)
  const int ce = (lane & 3) * 8;         // staging k-elem offset
  const int arow = (w >> 1) * 64, brow = (w & 1) * 64;
  const int mbase = Mtile + arow;

  const float* esq = e_sq + n * KCODES;
  __half* tmn = tm + (size_t)n * (BROWS * NWIN);

  float eq[4][4];
  #pragma unroll
  for (int mf = 0; mf < 4; ++mf) {
    int kb = mbase + mf * 16 + quad * 4;
    #pragma unroll
    for (int i = 0; i < 4; ++i) eq[mf][i] = esq[kb + i];
  }

  for (int nt = 0; nt < 4; ++nt) {
    const int Ntile = (blockIdx.y * 4 + nt) * 128;

    floatx4 acc[4][4];
    #pragma unroll
    for (int i = 0; i < 4; ++i)
      #pragma unroll
      for (int j = 0; j < 4; ++j) acc[i][j] = (floatx4){0.f, 0.f, 0.f, 0.f};

    for (int k0 = 0; k0 < DSUB; k0 += 32) {
      __syncthreads();   // also protects LDS reuse across nt iterations
      gl2lds16(ebase + (size_t)(Mtile + r0) * DSUB + k0 + ce,      As + w * 1024);
      gl2lds16(ebase + (size_t)(Mtile + r0 + 16) * DSUB + k0 + ce, As + w * 1024 + 512);
      gl2lds16(zbase + (size_t)(Ntile + r0) * DSUB + k0 + ce,      Bs + w * 1024);
      gl2lds16(zbase + (size_t)(Ntile + r0 + 16) * DSUB + k0 + ce, Bs + w * 1024 + 512);
      __syncthreads();

      short8 a[4], b[4];
      #pragma unroll
      for (int mf = 0; mf < 4; ++mf) a[mf] = *(const short8*)&As[(arow + mf * 16 + c16) * 32 + quad * 8];
      #pragma unroll
      for (int nf = 0; nf < 4; ++nf) b[nf] = *(const short8*)&Bs[(brow + nf * 16 + c16) * 32 + quad * 8];
      #pragma unroll
      for (int mf = 0; mf < 4; ++mf)
        #pragma unroll
        for (int nf = 0; nf < 4; ++nf)
          acc[mf][nf] = __builtin_amdgcn_mfma_f32_16x16x32_bf16(a[mf], b[nf], acc[mf][nf], 0, 0, 0);
    }

    // epilogue: per-mf (16-code window) min of e_sq[k] - 2*c, per z-row column
    const int nbase = Ntile + brow;
    #pragma unroll
    for (int nf = 0; nf < 4; ++nf) {
      float vm[4];
      #pragma unroll
      for (int mf = 0; mf < 4; ++mf) {
        float v = eq[mf][0] - 2.0f * acc[mf][nf][0];
        v = fminf(v, eq[mf][1] - 2.0f * acc[mf][nf][1]);
        v = fminf(v, eq[mf][2] - 2.0f * acc[mf][nf][2]);
        v = fminf(v, eq[mf][3] - 2.0f * acc[mf][nf][3]);
        v = fminf(v, __shfl_xor(v, 16, 64));
        v = fminf(v, __shfl_xor(v, 32, 64));
        vm[mf] = v;
      }
      if (quad == 0) {
        int zr = nbase + nf * 16 + c16;
        ushort4 o;
        o.x = __half_as_ushort(__float2half(vm[0]));
        o.y = __half_as_ushort(__float2half(vm[1]));
        o.z = __half_as_ushort(__float2half(vm[2]));
        o.w = __half_as_ushort(__float2half(vm[3]));
        *(ushort4*)&tmn[(size_t)zr * NWIN + (mbase >> 4)] = o;
      }
    }
  }
}

// ------------------------------------------------------------ pass B (exact + gather)
// 1024 blocks x 4 waves; each WAVE owns 4 rows, no __syncthreads.
// Per row: ballot-select 16-code windows with tm <= min+EPS; rescore exactly
// (4 lanes per code); lowest-k ties; write quantized row + index + loss.
__global__ __launch_bounds__(256)
void passB_kernel(const float* __restrict__ z, const float* __restrict__ emb,
                  const float* __restrict__ e_sq, const float* __restrict__ z_sq,
                  const __half* __restrict__ tm, float* __restrict__ out,
                  int* __restrict__ counts, float* __restrict__ loss) {
  const int w    = threadIdx.x >> 6, lane = threadIdx.x & 63;
  const int gw   = blockIdx.x * 4 + w;  // 0..4095
  const int q    = lane & 3;            // dim-quarter within code group
  const int g    = lane >> 2;           // code group 0..15
  float lossacc  = 0.f;

  for (int i = 0; i < 4; ++i) {
    const int row = gw * 4 + i;         // rz = b*2 + n
    const int n = row & 1, b = row >> 1;
    const float* ebase = emb + (size_t)n * KCODES * DSUB;
    const float* esq   = e_sq + n * KCODES;

    // threshold from tm row (8 fp16 per lane)
    const __half* tmr = tm + ((size_t)n * BROWS + b) * NWIN;
    uint4 tq = *(const uint4*)(tmr + lane * 8);
    float t[8];
    {
      __half2 h;
      h = *(__half2*)&tq.x; t[0] = __low2float(h); t[1] = __high2float(h);
      h = *(__half2*)&tq.y; t[2] = __low2float(h); t[3] = __high2float(h);
      h = *(__half2*)&tq.z; t[4] = __low2float(h); t[5] = __high2float(h);
      h = *(__half2*)&tq.w; t[6] = __low2float(h); t[7] = __high2float(h);
    }
    float mv = t[0];
    #pragma unroll
    for (int j = 1; j < 8; ++j) mv = fminf(mv, t[j]);
    #pragma unroll
    for (int off = 32; off; off >>= 1) mv = fminf(mv, __shfl_xor(mv, off, 64));
    const float thr = mv + EPS;
    const float zsr = z_sq[row];

    float bestd = 3.4e38f;
    int   bestk = 0x7fffffff;
    #pragma unroll
    for (int j = 0; j < 8; ++j) {
      unsigned long long mbits = __ballot(t[j] <= thr);
      while (mbits) {
        int src = __ffsll(mbits) - 1;
        mbits &= mbits - 1;
        int win  = src * 8 + j;
        int code = win * 16 + g;        // this group's code in the window
        const float4* ep = (const float4*)(ebase + (size_t)code * DSUB + q * 64);
        const float4* zp = (const float4*)(z + (size_t)row * DSUB + q * 64);
        float s = 0.f;
        #pragma unroll
        for (int u = 0; u < 16; ++u) {
          float4 ev = ep[u], zv = zp[u];
          s += ev.x * zv.x; s += ev.y * zv.y; s += ev.z * zv.z; s += ev.w * zv.w;
        }
        s += __shfl_xor(s, 1, 64);
        s += __shfl_xor(s, 2, 64);
        float dist = (zsr - 2.0f * s) + esq[code];
        if (dist < bestd || (dist == bestd && code < bestk)) { bestd = dist; bestk = code; }
      }
    }
    // wave argmin + lowest-k tie-break (result lands in all lanes)
    #pragma unroll
    for (int off = 1; off < 64; off <<= 1) {
      float d2 = __shfl_xor(bestd, off, 64);
      int   k2 = __shfl_xor(bestk, off, 64);
      if (d2 < bestd || (d2 == bestd && k2 < bestk)) { bestd = d2; bestk = k2; }
    }
    const int bk = bestk;

    // gather quantized row + commitment loss partial
    float4 ev = ((const float4*)(ebase + (size_t)bk * DSUB))[lane];
    float4 zv = ((const float4*)(z + (size_t)row * DSUB))[lane];
    ((float4*)(out + (size_t)row * DSUB))[lane] = ev;
    float dx = zv.x - ev.x, dy = zv.y - ev.y, dz = zv.z - ev.z, dw = zv.w - ev.w;
    float d = dx * dx + dy * dy + dz * dz + dw * dw;
    #pragma unroll
    for (int off = 32; off; off >>= 1) d += __shfl_xor(d, off, 64);
    lossacc += d;
    if (lane == 0) {
      out[IDX_OFF + row] = (float)bk;
      atomicAdd(&counts[n * KCODES + bk], 1);
    }
  }
  if (lane == 0) atomicAdd(loss, lossacc);
}

// ------------------------------------------------------------ final kernel
__global__ void final_kernel(const int* __restrict__ counts, const float* __restrict__ loss,
                             float* __restrict__ out) {
  __shared__ float red[256];
  float h = 0.0f;
  for (int k = threadIdx.x; k < KCODES; k += 256) {
    float p = (float)(counts[k] + counts[KCODES + k]) * (1.0f / 16384.0f);
    h -= p * logf(p + 1e-10f);
  }
  red[threadIdx.x] = h;
  __syncthreads();
  for (int s = 128; s; s >>= 1) {
    if (threadIdx.x < s) red[threadIdx.x] += red[threadIdx.x + s];
    __syncthreads();
  }
  if (threadIdx.x == 0) {
    out[LOSS_OFF + 0] = 0.25f * loss[0] * (1.0f / (float)QUANT_N);
    out[LOSS_OFF + 1] = 0.0f;
    out[LOSS_OFF + 2] = expf(red[0]);
  }
}

extern "C" void kernel_launch(void* const* d_in, const int* in_sizes, int n_in,
                              void* d_out, int out_size, void* d_ws, size_t ws_size,
                              hipStream_t stream) {
  const float* z   = (const float*)d_in[0];
  const float* emb = (const float*)d_in[1];
  float* out = (float*)d_out;
  char*  ws  = (char*)d_ws;

  float* e_sq   = (float*)(ws + WS_ESQ);
  float* z_sq   = (float*)(ws + WS_ZSQ);
  int*   counts = (int*)(ws + WS_COUNTS);
  float* loss   = (float*)(ws + WS_LOSS);
  unsigned short* zb = (unsigned short*)(ws + WS_ZBF);
  unsigned short* eb = (unsigned short*)(ws + WS_EBF);
  __half* tmbuf = (__half*)(ws + WS_TM);

  hipMemsetAsync(ws + WS_COUNTS, 0, 65536 + 16, stream);
  prep_kernel<<<1024, 256, 0, stream>>>(z, emb, e_sq, z_sq, zb, eb);
  dim3 gA(64, 16, 2);
  passA_kernel<<<gA, 256, 0, stream>>>(zb, eb, e_sq, tmbuf);
  passB_kernel<<<1024, 256, 0, stream>>>(z, emb, e_sq, z_sq, tmbuf, out, counts, loss);
  final_kernel<<<1, 256, 0, stream>>>(counts, loss, out);
}